// Round 1
// baseline (3155.112 us; speedup 1.0000x reference)
//
#include <hip/hip_runtime.h>
#include <hip/hip_bf16.h>

// CGCNN conv ×4 on MI355X.
// Decomposition: total = P_self[self] + P_nbr[nbr] + nbr_fea@W_nf + b,
// where P = x @ [W_self | W_nbr] is per-node (N=50k) not per-edge (E=800k).
// BN1 stats via pass-1 (no store), recompute in pass-2.
// ws layout (floats): x[N*64] | P[N*256] | summed[N*64] | stats[768]
// stats: sum1[128] ssq1[128] scale1[128] shift1[128] sum2[64] ssq2[64] scale2[64] shift2[64]

#define WAVE 64

__device__ __forceinline__ float readlane_f(float v, int l) {
  union { float f; int i; } u; u.f = v;
  u.i = __builtin_amdgcn_readlane(u.i, l);
  return u.f;
}

__device__ __forceinline__ float softplus_f(float x) {
  // jax.nn.softplus = max(x,0) + log1p(exp(-|x|))
  return fmaxf(x, 0.f) + log1pf(__expf(-fabsf(x)));
}
__device__ __forceinline__ float sigmoid_f(float x) {
  return 1.f / (1.f + __expf(-x));
}

// x[n][j] = sum_k atom[n][k] * W[k][j] + b[j];  one wave per node
__global__ void embed_k(const float* __restrict__ atom, const float* __restrict__ W,
                        const float* __restrict__ b, float* __restrict__ x, int N) {
  const int lane = threadIdx.x & 63;
  const long nw = (long)gridDim.x * 4;
  const long wid = (long)blockIdx.x * 4 + (threadIdx.x >> 6);
  float w[92];
#pragma unroll
  for (int k = 0; k < 92; ++k) w[k] = W[k * 64 + lane];
  const float bias = b[lane];
  for (long n = wid; n < N; n += nw) {
    const float a0 = atom[n * 92 + lane];
    const float a1 = (lane < 28) ? atom[n * 92 + 64 + lane] : 0.f;
    float acc0 = bias, acc1 = 0.f;
#pragma unroll
    for (int k = 0; k < 64; k += 2) {
      acc0 = fmaf(readlane_f(a0, k),     w[k],     acc0);
      acc1 = fmaf(readlane_f(a0, k + 1), w[k + 1], acc1);
    }
#pragma unroll
    for (int k = 0; k < 28; k += 2) {
      acc0 = fmaf(readlane_f(a1, k),     w[64 + k],     acc0);
      acc1 = fmaf(readlane_f(a1, k + 1), w[64 + k + 1], acc1);
    }
    x[n * 64 + lane] = acc0 + acc1;
  }
}

// P[n][0:128] = x[n] @ fcW[0:64][:], P[n][128:256] = x[n] @ fcW[64:128][:]
// one wave per (node, half); lane owns cols (2j, 2j+1) of the half.
__global__ void p_k(const float* __restrict__ x, const float* __restrict__ fcW,
                    float* __restrict__ P, int N) {
  const int lane = threadIdx.x & 63;
  const long nw = (long)gridDim.x * 4;
  const long wid = (long)blockIdx.x * 4 + (threadIdx.x >> 6);
  const int half = (int)(wid & 1);  // nw even -> constant per wave
  float2 wp[64];
  const float2* W2 = (const float2*)fcW;
#pragma unroll
  for (int k = 0; k < 64; ++k) wp[k] = W2[(half * 64 + k) * 64 + lane];
  for (long t = wid; t < 2L * N; t += nw) {
    const long n = t >> 1;
    const float xl = x[n * 64 + lane];
    float a0 = 0.f, a1 = 0.f, a2 = 0.f, a3 = 0.f;
#pragma unroll
    for (int k = 0; k < 64; k += 2) {
      const float xk0 = readlane_f(xl, k);
      const float xk1 = readlane_f(xl, k + 1);
      a0 = fmaf(xk0, wp[k].x, a0);
      a1 = fmaf(xk0, wp[k].y, a1);
      a2 = fmaf(xk1, wp[k + 1].x, a2);
      a3 = fmaf(xk1, wp[k + 1].y, a3);
    }
    ((float2*)P)[n * 128 + half * 64 + lane] = make_float2(a0 + a2, a1 + a3);
  }
}

// PHASE 1: accumulate per-column sum/sumsq of pre-BN "total".
// PHASE 2: apply BN1, msg = sigmoid(filt)*softplus(core), atomic segment-sum.
// One wave per edge; lane j owns cols j (filt) and j+64 (core).
template <int PHASE>
__global__ void edge_k(const float* __restrict__ P, const float* __restrict__ nbr_fea,
                       const int* __restrict__ self_idx, const int* __restrict__ nbr_idx,
                       const float* __restrict__ fcW, const float* __restrict__ fcb,
                       float* __restrict__ stats, float* __restrict__ summed, int E) {
  const int tid = threadIdx.x;
  const int lane = tid & 63;
  const long nw = (long)gridDim.x * 4;
  const long wid = (long)blockIdx.x * 4 + (tid >> 6);

  float wf[41], wc[41];
#pragma unroll
  for (int k = 0; k < 41; ++k) {
    wf[k] = fcW[(128 + k) * 128 + lane];
    wc[k] = fcW[(128 + k) * 128 + 64 + lane];
  }
  const float bf = fcb[lane], bc = fcb[64 + lane];
  float sc_f = 0.f, sh_f = 0.f, sc_c = 0.f, sh_c = 0.f;
  if (PHASE == 2) {
    sc_f = stats[256 + lane];      sh_f = stats[384 + lane];
    sc_c = stats[256 + 64 + lane]; sh_c = stats[384 + 64 + lane];
  }
  float sum_f = 0.f, ssq_f = 0.f, sum_c = 0.f, ssq_c = 0.f;

  for (long e = wid; e < E; e += nw) {
    const int s = self_idx[e];
    const int nn = nbr_idx[e];
    float fl = 0.f;
    if (lane < 41) fl = nbr_fea[e * 41 + lane];
    const float g0 = P[(long)s * 256 + lane];
    const float g1 = P[(long)s * 256 + 64 + lane];
    const float g2 = P[(long)nn * 256 + 128 + lane];
    const float g3 = P[(long)nn * 256 + 192 + lane];
    float af0 = 0.f, af1 = 0.f, ac0 = 0.f, ac1 = 0.f;
#pragma unroll
    for (int k = 0; k < 40; k += 2) {
      const float fk0 = readlane_f(fl, k);
      const float fk1 = readlane_f(fl, k + 1);
      af0 = fmaf(fk0, wf[k], af0);
      ac0 = fmaf(fk0, wc[k], ac0);
      af1 = fmaf(fk1, wf[k + 1], af1);
      ac1 = fmaf(fk1, wc[k + 1], ac1);
    }
    {
      const float fk = readlane_f(fl, 40);
      af0 = fmaf(fk, wf[40], af0);
      ac0 = fmaf(fk, wc[40], ac0);
    }
    const float tf = g0 + g2 + bf + (af0 + af1);
    const float tc = g1 + g3 + bc + (ac0 + ac1);
    if (PHASE == 1) {
      sum_f += tf; ssq_f = fmaf(tf, tf, ssq_f);
      sum_c += tc; ssq_c = fmaf(tc, tc, ssq_c);
    } else {
      const float uf = fmaf(tf, sc_f, sh_f);
      const float uc = fmaf(tc, sc_c, sh_c);
      const float msg = sigmoid_f(uf) * softplus_f(uc);
      atomicAdd(&summed[(long)s * 64 + lane], msg);
    }
  }

  if (PHASE == 1) {
    __shared__ float4 red[256];
    red[tid] = make_float4(sum_f, ssq_f, sum_c, ssq_c);
    __syncthreads();
    if (tid < 64) {
      const float4 a = red[tid], b2 = red[tid + 64], c = red[tid + 128], d = red[tid + 192];
      atomicAdd(&stats[tid],            a.x + b2.x + c.x + d.x);  // sum filt col tid
      atomicAdd(&stats[128 + tid],      a.y + b2.y + c.y + d.y);  // ssq filt
      atomicAdd(&stats[64 + tid],       a.z + b2.z + c.z + d.z);  // sum core col 64+tid
      atomicAdd(&stats[128 + 64 + tid], a.w + b2.w + c.w + d.w);  // ssq core
    }
  }
}

__global__ void fin1_k(float* __restrict__ stats, const float* __restrict__ g,
                       const float* __restrict__ b, int E) {
  const int c = threadIdx.x;  // 0..127
  const float mean = stats[c] / (float)E;
  const float var = stats[128 + c] / (float)E - mean * mean;
  const float sc = g[c] * rsqrtf(var + 1e-5f);
  stats[256 + c] = sc;
  stats[384 + c] = fmaf(-mean, sc, b[c]);
}

__global__ void bn2_stats_k(const float* __restrict__ summed, float* __restrict__ stats, int N) {
  const int tid = threadIdx.x;
  const int j = tid & 63;
  const int r = tid >> 6;
  float s = 0.f, q = 0.f;
  for (long n = (long)blockIdx.x * 4 + r; n < N; n += (long)gridDim.x * 4) {
    const float v = summed[n * 64 + j];
    s += v; q = fmaf(v, v, q);
  }
  __shared__ float2 red[256];
  red[tid] = make_float2(s, q);
  __syncthreads();
  if (tid < 64) {
    const float2 a = red[tid], b2 = red[tid + 64], c = red[tid + 128], d = red[tid + 192];
    atomicAdd(&stats[512 + tid], a.x + b2.x + c.x + d.x);
    atomicAdd(&stats[576 + tid], a.y + b2.y + c.y + d.y);
  }
}

__global__ void fin2_k(float* __restrict__ stats, const float* __restrict__ g,
                       const float* __restrict__ b, int N) {
  const int c = threadIdx.x;  // 0..63
  const float mean = stats[512 + c] / (float)N;
  const float var = stats[576 + c] / (float)N - mean * mean;
  const float sc = g[c] * rsqrtf(var + 1e-5f);
  stats[640 + c] = sc;
  stats[704 + c] = fmaf(-mean, sc, b[c]);
}

__global__ void upd_k(const float* __restrict__ x, const float* __restrict__ summed,
                      const float* __restrict__ stats, float* __restrict__ dst, int total) {
  const int idx = blockIdx.x * 256 + threadIdx.x;
  if (idx >= total) return;
  const int j = idx & 63;
  const float v = x[idx] + fmaf(summed[idx], stats[640 + j], stats[704 + j]);
  dst[idx] = softplus_f(v);
}

extern "C" void kernel_launch(void* const* d_in, const int* in_sizes, int n_in,
                              void* d_out, int out_size, void* d_ws, size_t ws_size,
                              hipStream_t stream) {
  const float* atom_fea = (const float*)d_in[0];
  const float* nbr_fea  = (const float*)d_in[1];
  const int*   self_idx = (const int*)d_in[2];
  const int*   nbr_idx  = (const int*)d_in[3];
  const float* emb_W    = (const float*)d_in[4];
  const float* emb_b    = (const float*)d_in[5];
  const float* fc_W     = (const float*)d_in[6];
  const float* fc_b     = (const float*)d_in[7];
  const float* bn1_g    = (const float*)d_in[8];
  const float* bn1_b    = (const float*)d_in[9];
  const float* bn2_g    = (const float*)d_in[10];
  const float* bn2_b    = (const float*)d_in[11];
  float* out = (float*)d_out;

  const int N = in_sizes[0] / 92;
  const int E = in_sizes[2];

  float* x      = (float*)d_ws;
  float* P      = x + (size_t)N * 64;
  float* summed = P + (size_t)N * 256;
  float* stats  = summed + (size_t)N * 64;

  embed_k<<<256, 256, 0, stream>>>(atom_fea, emb_W, emb_b, x, N);

  for (int i = 0; i < 4; ++i) {
    const float* Wi = fc_W + (size_t)i * 169 * 128;
    const float* bi = fc_b + (size_t)i * 128;
    hipMemsetAsync(summed, 0, ((size_t)N * 64 + 768) * sizeof(float), stream);
    p_k<<<512, 256, 0, stream>>>(x, Wi, P, N);
    edge_k<1><<<1024, 256, 0, stream>>>(P, nbr_fea, self_idx, nbr_idx, Wi, bi, stats, summed, E);
    fin1_k<<<1, 128, 0, stream>>>(stats, bn1_g + (size_t)i * 128, bn1_b + (size_t)i * 128, E);
    edge_k<2><<<1024, 256, 0, stream>>>(P, nbr_fea, self_idx, nbr_idx, Wi, bi, stats, summed, E);
    bn2_stats_k<<<256, 256, 0, stream>>>(summed, stats, N);
    fin2_k<<<1, 64, 0, stream>>>(stats, bn2_g + (size_t)i * 64, bn2_b + (size_t)i * 64, N);
    float* dst = (i == 3) ? out : x;
    upd_k<<<(N * 64 + 255) / 256, 256, 0, stream>>>(x, summed, stats, dst, N * 64);
  }
}